// Round 5
// baseline (613.677 us; speedup 1.0000x reference)
//
#include <hip/hip_runtime.h>
#include <stdint.h>

#define HD 2048
#define FD 1024
#define NE 16
#define NPAIR 8192
#define BM 256
#define MAXT 48
#define LDK 40   // 32 el + 8 pad: 80 B row stride, 16B-aligned for b128, 2-way-free banks

typedef short bf16x8 __attribute__((ext_vector_type(8)));
typedef float f32x4 __attribute__((ext_vector_type(4)));
typedef unsigned short u16;

static __device__ __forceinline__ u16 f2bf(float f) {
  uint32_t u = __float_as_uint(f);
  u += 0x7FFFu + ((u >> 16) & 1u);
  return (u16)(u >> 16);
}

// Scale-folded byte tables for e2m1 -> bf16 dequant via v_perm.
// scale = 2^n (e8m0, n in [-8,-6] for this problem, always negative).
// n = 2q + r: r selects value-table (x1 or x2), q subtracted from hi(exponent) bytes.
struct DqTab { uint32_t hA, hB, lA, lB; };

static __device__ __forceinline__ DqTab make_tab(uint32_t sbits) {
  int n = (int)(sbits >> 23) - 127;
  int q = n >> 1;            // arithmetic shift
  uint32_t r = (uint32_t)(n & 1);
  uint32_t mq = (uint32_t)(-q);   // q < 0 always (scales < 1)
  uint32_t sub1 = mq * 0x01010100u;  // entry 0 (zero) untouched
  uint32_t subA = mq * 0x01010101u;
  DqTab t;
  // hi bytes of bf16({0,.5,1,1.5,2,3,4,6}) or x2 table {0,1,2,3,4,6,8,12}
  t.hA = (r ? 0x40403F00u : 0x3F3F3F00u) - sub1;
  t.hB = (r ? 0x41414040u : 0x40404040u) - subA;
  // lo bytes (mantissa) — unaffected by power-of-two scale
  t.lA = r ? 0x40008000u : 0xC0800000u;
  t.lB = r ? 0x4000C080u : 0xC0804000u;
  return t;
}

// p: 4 packed fp4 bytes (8 values, low nibble first). d[0..3]: packed bf16 pairs.
static __device__ __forceinline__ void dq8(uint32_t p, const DqTab& t, uint32_t* d) {
  uint32_t a = p & 0x0F0F0F0Fu;          // nibbles 0,2,4,6 (sign in bit3)
  uint32_t b = (p >> 4) & 0x0F0F0F0Fu;   // nibbles 1,3,5,7
  uint32_t x0 = __builtin_amdgcn_perm(b, a, 0x05010400u);  // [n0,n1,n2,n3]
  uint32_t x1 = __builtin_amdgcn_perm(b, a, 0x07030602u);  // [n4,n5,n6,n7]
  uint32_t m0 = x0 & 0x07070707u;
  uint32_t m1 = x1 & 0x07070707u;
  uint32_t h0 = __builtin_amdgcn_perm(t.hB, t.hA, m0) | ((x0 & 0x08080808u) << 4);
  uint32_t h1 = __builtin_amdgcn_perm(t.hB, t.hA, m1) | ((x1 & 0x08080808u) << 4);
  uint32_t l0 = __builtin_amdgcn_perm(t.lB, t.lA, m0);
  uint32_t l1 = __builtin_amdgcn_perm(t.lB, t.lA, m1);
  d[0] = __builtin_amdgcn_perm(h0, l0, 0x05010400u);
  d[1] = __builtin_amdgcn_perm(h0, l0, 0x07030602u);
  d[2] = __builtin_amdgcn_perm(h1, l1, 0x05010400u);
  d[3] = __builtin_amdgcn_perm(h1, l1, 0x07030602u);
}

// weights uploaded as one int32 per packed byte -> gather 4 bytes into a dword
static __device__ __forceinline__ uint32_t pack4(int4 v) {
  return (uint32_t)(v.x & 0xFF) | ((uint32_t)(v.y & 0xFF) << 8) |
         ((uint32_t)(v.z & 0xFF) << 16) | ((uint32_t)v.w << 24);
}

__global__ void cast_kernel(const float* __restrict__ x, u16* __restrict__ xb) {
  int i = blockIdx.x * 256 + threadIdx.x;
  float4 v = ((const float4*)x)[i];
  ushort4 o;
  o.x = f2bf(v.x); o.y = f2bf(v.y); o.z = f2bf(v.z); o.w = f2bf(v.w);
  ((ushort4*)xb)[i] = o;
}

__global__ void zero_kernel(float4* __restrict__ out) {
  out[blockIdx.x * 256 + threadIdx.x] = float4{0.f, 0.f, 0.f, 0.f};
}

__global__ void route_kernel(const int* __restrict__ ids, const float* __restrict__ tw,
                             int* __restrict__ rows, float* __restrict__ rw,
                             int* __restrict__ te) {
  __shared__ int cnt[NE], base[NE], run[NE];
  int tid = threadIdx.x;
  if (tid < NE) { cnt[tid] = 0; run[tid] = 0; }
  __syncthreads();
  for (int i = tid; i < NPAIR; i += 256) atomicAdd(&cnt[ids[i]], 1);
  __syncthreads();
  if (tid == 0) {
    int cum = 0;
    for (int e = 0; e < NE; ++e) {
      base[e] = cum;
      int nt = (cnt[e] + BM - 1) >> 8;
      for (int j = 0; j < nt; ++j) te[(cum >> 8) + j] = e;
      cum += nt << 8;
    }
    for (int t = cum >> 8; t < MAXT; ++t) te[t] = -1;
  }
  __syncthreads();
  for (int i = tid; i < MAXT * BM; i += 256) { rows[i] = -1; rw[i] = 0.f; }
  __syncthreads();
  for (int i = tid; i < NPAIR; i += 256) {
    int e = ids[i];
    int p = base[e] + atomicAdd(&run[e], 1);
    rows[p] = i >> 2;
    rw[p] = tw[i];
  }
}

// gate_up GEMM + SwiGLU + routing weight -> act (bf16). BM=256, BN=64(g)+64(u), BK=32.
__global__ __launch_bounds__(256, 2) void gemm1_kernel(
    const u16* __restrict__ xb, const int* __restrict__ gup32,
    const uint32_t* __restrict__ gus, const int* __restrict__ rows,
    const float* __restrict__ rw, const int* __restrict__ te,
    u16* __restrict__ act) {
  const int tile = blockIdx.y;
  const int e = te[tile];
  if (e < 0) return;
  const int f0 = blockIdx.x * 64;

  __shared__ u16 sA[BM * LDK];
  __shared__ u16 sBg[64 * LDK];
  __shared__ u16 sBu[64 * LDK];
  __shared__ int rows_s[BM];
  __shared__ float rw_s[BM];

  const int tid = threadIdx.x;
  rows_s[tid] = rows[tile * BM + tid];
  rw_s[tid] = rw[tile * BM + tid];
  __syncthreads();

  int arow = rows_s[tid];
  arow = arow < 0 ? 0 : arow;
  const u16* aptr = xb + (size_t)arow * HD;
  u16* sAp = &sA[tid * LDK];

  const int bn = (tid & 127) >> 1;
  const int isUp = tid >> 7;
  const int o = isUp * 1024 + f0 + bn;
  const int skh = tid & 1;
  const int* bptr = gup32 + (size_t)(e * 2048 + o) * (HD / 2) + skh * 8;
  const uint32_t* sptr = gus + (size_t)(e * 2048 + o) * (HD / 32);
  u16* sBp = (isUp ? sBu : sBg) + bn * LDK + skh * 16;

  const int lane = tid & 63;
  const int w = tid >> 6;
  const int q = lane >> 4, c = lane & 15;

  f32x4 Cg[4][4], Cu[4][4];
#pragma unroll
  for (int s = 0; s < 4; ++s)
#pragma unroll
    for (int t2 = 0; t2 < 4; ++t2) {
      Cg[s][t2] = f32x4{0.f, 0.f, 0.f, 0.f};
      Cu[s][t2] = f32x4{0.f, 0.f, 0.f, 0.f};
    }

  for (int kk = 0; kk < HD; kk += 32) {
    uint4 a0 = *(const uint4*)(aptr + kk);
    uint4 a1 = *(const uint4*)(aptr + kk + 8);
    uint4 a2 = *(const uint4*)(aptr + kk + 16);
    uint4 a3 = *(const uint4*)(aptr + kk + 24);
    int4 w0 = *(const int4*)(bptr + (kk >> 1));
    int4 w1 = *(const int4*)(bptr + (kk >> 1) + 4);
    uint32_t sb = sptr[kk >> 5];
    DqTab t = make_tab(sb);
    uint32_t d0[4], d1[4];
    dq8(pack4(w0), t, d0);
    dq8(pack4(w1), t, d1);
    *(uint4*)sAp = a0;
    *(uint4*)(sAp + 8) = a1;
    *(uint4*)(sAp + 16) = a2;
    *(uint4*)(sAp + 24) = a3;
    *(uint4*)sBp = make_uint4(d0[0], d0[1], d0[2], d0[3]);
    *(uint4*)(sBp + 8) = make_uint4(d1[0], d1[1], d1[2], d1[3]);
    __syncthreads();

    bf16x8 af[4], bg[4], bu[4];
#pragma unroll
    for (int s = 0; s < 4; ++s)
      af[s] = *(const bf16x8*)&sA[(w * 64 + s * 16 + c) * LDK + q * 8];
#pragma unroll
    for (int t2 = 0; t2 < 4; ++t2) {
      bg[t2] = *(const bf16x8*)&sBg[(t2 * 16 + c) * LDK + q * 8];
      bu[t2] = *(const bf16x8*)&sBu[(t2 * 16 + c) * LDK + q * 8];
    }
#pragma unroll
    for (int s = 0; s < 4; ++s)
#pragma unroll
      for (int t2 = 0; t2 < 4; ++t2) {
        Cg[s][t2] = __builtin_amdgcn_mfma_f32_16x16x32_bf16(af[s], bg[t2], Cg[s][t2], 0, 0, 0);
        Cu[s][t2] = __builtin_amdgcn_mfma_f32_16x16x32_bf16(af[s], bu[t2], Cu[s][t2], 0, 0, 0);
      }
    __syncthreads();
  }

#pragma unroll
  for (int s = 0; s < 4; ++s) {
    const int mlb = w * 64 + s * 16 + q * 4;
#pragma unroll
    for (int t2 = 0; t2 < 4; ++t2) {
      const int fg = f0 + t2 * 16 + c;
#pragma unroll
      for (int r = 0; r < 4; ++r) {
        const int ml = mlb + r;
        float g = Cg[s][t2][r];
        float u = Cu[s][t2][r];
        float aval = g / (1.f + __expf(-g)) * u * rw_s[ml];
        act[(size_t)(tile * BM + ml) * FD + fg] = f2bf(aval);
      }
    }
  }
}

// down GEMM, atomic accumulate into out. BM=256, BN=128, BK=32.
__global__ __launch_bounds__(256, 2) void gemm2_kernel(
    const u16* __restrict__ act, const int* __restrict__ dwn32,
    const uint32_t* __restrict__ dsc, const int* __restrict__ rows,
    const int* __restrict__ te, float* __restrict__ out) {
  const int tile = blockIdx.y;
  const int e = te[tile];
  if (e < 0) return;
  const int h0 = blockIdx.x * 128;

  __shared__ u16 sA[BM * LDK];
  __shared__ u16 sB[128 * LDK];
  __shared__ int rows_s[BM];

  const int tid = threadIdx.x;
  rows_s[tid] = rows[tile * BM + tid];
  __syncthreads();

  const u16* aptr = act + (size_t)(tile * BM + tid) * FD;
  u16* sAp = &sA[tid * LDK];

  const int bn = tid >> 1;
  const int skh = tid & 1;
  const int* bptr = dwn32 + (size_t)(e * 2048 + h0 + bn) * (FD / 2) + skh * 8;
  const uint32_t* sptr = dsc + (size_t)(e * 2048 + h0 + bn) * (FD / 32);
  u16* sBp = &sB[bn * LDK + skh * 16];

  const int lane = tid & 63;
  const int w = tid >> 6;
  const int q = lane >> 4, c = lane & 15;

  f32x4 Cd[4][8];
#pragma unroll
  for (int s = 0; s < 4; ++s)
#pragma unroll
    for (int t2 = 0; t2 < 8; ++t2) Cd[s][t2] = f32x4{0.f, 0.f, 0.f, 0.f};

  for (int kk = 0; kk < FD; kk += 32) {
    uint4 a0 = *(const uint4*)(aptr + kk);
    uint4 a1 = *(const uint4*)(aptr + kk + 8);
    uint4 a2 = *(const uint4*)(aptr + kk + 16);
    uint4 a3 = *(const uint4*)(aptr + kk + 24);
    int4 w0 = *(const int4*)(bptr + (kk >> 1));
    int4 w1 = *(const int4*)(bptr + (kk >> 1) + 4);
    uint32_t sb = sptr[kk >> 5];
    DqTab t = make_tab(sb);
    uint32_t d0[4], d1[4];
    dq8(pack4(w0), t, d0);
    dq8(pack4(w1), t, d1);
    *(uint4*)sAp = a0;
    *(uint4*)(sAp + 8) = a1;
    *(uint4*)(sAp + 16) = a2;
    *(uint4*)(sAp + 24) = a3;
    *(uint4*)sBp = make_uint4(d0[0], d0[1], d0[2], d0[3]);
    *(uint4*)(sBp + 8) = make_uint4(d1[0], d1[1], d1[2], d1[3]);
    __syncthreads();

    bf16x8 af[4], bf_[8];
#pragma unroll
    for (int s = 0; s < 4; ++s)
      af[s] = *(const bf16x8*)&sA[(w * 64 + s * 16 + c) * LDK + q * 8];
#pragma unroll
    for (int t2 = 0; t2 < 8; ++t2)
      bf_[t2] = *(const bf16x8*)&sB[(t2 * 16 + c) * LDK + q * 8];
#pragma unroll
    for (int s = 0; s < 4; ++s)
#pragma unroll
      for (int t2 = 0; t2 < 8; ++t2)
        Cd[s][t2] = __builtin_amdgcn_mfma_f32_16x16x32_bf16(af[s], bf_[t2], Cd[s][t2], 0, 0, 0);
    __syncthreads();
  }

#pragma unroll
  for (int s = 0; s < 4; ++s) {
    const int mlb = w * 64 + s * 16 + q * 4;
#pragma unroll
    for (int t2 = 0; t2 < 8; ++t2) {
      const int hg = h0 + t2 * 16 + c;
#pragma unroll
      for (int r = 0; r < 4; ++r) {
        int token = rows_s[mlb + r];
        if (token >= 0) atomicAdd(&out[(size_t)token * HD + hg], Cd[s][t2][r]);
      }
    }
  }
}

extern "C" void kernel_launch(void* const* d_in, const int* in_sizes, int n_in,
                              void* d_out, int out_size, void* d_ws, size_t ws_size,
                              hipStream_t stream) {
  const float* hidden = (const float*)d_in[0];
  const float* tw = (const float*)d_in[1];
  const int* ids = (const int*)d_in[2];
  const int* gup32 = (const int*)d_in[3];        // uint8 packed bytes, uploaded as int32
  const uint32_t* gus = (const uint32_t*)d_in[4];
  const int* dwn32 = (const int*)d_in[5];
  const uint32_t* dsc = (const uint32_t*)d_in[6];
  float* out = (float*)d_out;

  char* ws = (char*)d_ws;
  int* rows = (int*)(ws);                    // 48 KB
  float* rw = (float*)(ws + 49152);          // 48 KB
  int* te = (int*)(ws + 98304);              // 192 B
  u16* xb = (u16*)(ws + 131072);             // 8 MB
  u16* act = (u16*)(ws + 8519680);           // up to 25.2 MB addressable; actual writes
                                             // = tiles_used*0.5MB (~20 MB) stay < 29.5 MB known-safe

  cast_kernel<<<dim3(4096), dim3(256), 0, stream>>>(hidden, xb);
  zero_kernel<<<dim3(4096), dim3(256), 0, stream>>>((float4*)out);
  route_kernel<<<dim3(1), dim3(256), 0, stream>>>(ids, tw, rows, rw, te);
  gemm1_kernel<<<dim3(16, MAXT), dim3(256), 0, stream>>>(xb, gup32, gus, rows, rw, te, act);
  gemm2_kernel<<<dim3(16, MAXT), dim3(256), 0, stream>>>(act, dwn32, dsc, rows, te, out);
}

// Round 6
// 580.330 us; speedup vs baseline: 1.0575x; 1.0575x over previous
//
#include <hip/hip_runtime.h>
#include <stdint.h>

#define HD 2048
#define FD 1024
#define NE 16
#define NPAIR 8192
#define BM 256
#define MAXT 48
#define LDK 40   // 32 el + 8 pad: 80 B row stride, 16B-aligned for b128, 2-way-free banks

typedef short bf16x8 __attribute__((ext_vector_type(8)));
typedef float f32x4 __attribute__((ext_vector_type(4)));
typedef unsigned short u16;

static __device__ __forceinline__ u16 f2bf(float f) {
  uint32_t u = __float_as_uint(f);
  u += 0x7FFFu + ((u >> 16) & 1u);
  return (u16)(u >> 16);
}

// Scale-folded byte tables for e2m1 -> bf16 dequant via v_perm.
// scale = 2^n (e8m0, negative here). n = 2q + r: r selects x1/x2 value table,
// q subtracted from exponent bytes.
struct DqTab { uint32_t hA, hB, lA, lB; };

static __device__ __forceinline__ DqTab make_tab(uint32_t sbits) {
  int n = (int)(sbits >> 23) - 127;
  int q = n >> 1;
  uint32_t r = (uint32_t)(n & 1);
  uint32_t mq = (uint32_t)(-q);
  uint32_t sub1 = mq * 0x01010100u;  // entry 0 (zero) untouched
  uint32_t subA = mq * 0x01010101u;
  DqTab t;
  t.hA = (r ? 0x40403F00u : 0x3F3F3F00u) - sub1;
  t.hB = (r ? 0x41414040u : 0x40404040u) - subA;
  t.lA = r ? 0x40008000u : 0xC0800000u;
  t.lB = r ? 0x4000C080u : 0xC0804000u;
  return t;
}

// p: 4 packed fp4 bytes (8 values, low nibble first) -> 4 dwords of bf16 pairs
static __device__ __forceinline__ void dq8(uint32_t p, const DqTab& t, uint32_t* d) {
  uint32_t a = p & 0x0F0F0F0Fu;
  uint32_t b = (p >> 4) & 0x0F0F0F0Fu;
  uint32_t x0 = __builtin_amdgcn_perm(b, a, 0x05010400u);
  uint32_t x1 = __builtin_amdgcn_perm(b, a, 0x07030602u);
  uint32_t m0 = x0 & 0x07070707u;
  uint32_t m1 = x1 & 0x07070707u;
  uint32_t h0 = __builtin_amdgcn_perm(t.hB, t.hA, m0) | ((x0 & 0x08080808u) << 4);
  uint32_t h1 = __builtin_amdgcn_perm(t.hB, t.hA, m1) | ((x1 & 0x08080808u) << 4);
  uint32_t l0 = __builtin_amdgcn_perm(t.lB, t.lA, m0);
  uint32_t l1 = __builtin_amdgcn_perm(t.lB, t.lA, m1);
  d[0] = __builtin_amdgcn_perm(h0, l0, 0x05010400u);
  d[1] = __builtin_amdgcn_perm(h0, l0, 0x07030602u);
  d[2] = __builtin_amdgcn_perm(h1, l1, 0x05010400u);
  d[3] = __builtin_amdgcn_perm(h1, l1, 0x07030602u);
}

static __device__ __forceinline__ uint32_t pack4(int4 v) {
  return (uint32_t)(v.x & 0xFF) | ((uint32_t)(v.y & 0xFF) << 8) |
         ((uint32_t)(v.z & 0xFF) << 16) | ((uint32_t)v.w << 24);
}

__global__ void cast_kernel(const float* __restrict__ x, u16* __restrict__ xb) {
  int i = blockIdx.x * 256 + threadIdx.x;
  float4 v = ((const float4*)x)[i];
  ushort4 o;
  o.x = f2bf(v.x); o.y = f2bf(v.y); o.z = f2bf(v.z); o.w = f2bf(v.w);
  ((ushort4*)xb)[i] = o;
}

__global__ void zero_kernel(float4* __restrict__ out) {
  out[blockIdx.x * 256 + threadIdx.x] = float4{0.f, 0.f, 0.f, 0.f};
}

__global__ void route_kernel(const int* __restrict__ ids, const float* __restrict__ tw,
                             int* __restrict__ rows, float* __restrict__ rw,
                             int* __restrict__ te) {
  __shared__ int cnt[NE], base[NE], run[NE];
  int tid = threadIdx.x;
  if (tid < NE) { cnt[tid] = 0; run[tid] = 0; }
  __syncthreads();
  for (int i = tid; i < NPAIR; i += 256) atomicAdd(&cnt[ids[i]], 1);
  __syncthreads();
  if (tid == 0) {
    int cum = 0;
    for (int e = 0; e < NE; ++e) {
      base[e] = cum;
      int nt = (cnt[e] + BM - 1) >> 8;
      for (int j = 0; j < nt; ++j) te[(cum >> 8) + j] = e;
      cum += nt << 8;
    }
    for (int t = cum >> 8; t < MAXT; ++t) te[t] = -1;
  }
  __syncthreads();
  for (int i = tid; i < MAXT * BM; i += 256) { rows[i] = -1; rw[i] = 0.f; }
  __syncthreads();
  for (int i = tid; i < NPAIR; i += 256) {
    int e = ids[i];
    int p = base[e] + atomicAdd(&run[e], 1);
    rows[p] = i >> 2;
    rw[p] = tw[i];
  }
}

// gate_up GEMM + SwiGLU + routing weight -> act (bf16). BM=256, BN=64+64, BK=32.
// Double-buffered LDS, register prefetch, ONE barrier per K-step.
__global__ __launch_bounds__(256, 2) void gemm1_kernel(
    const u16* __restrict__ xb, const int* __restrict__ gup32,
    const uint32_t* __restrict__ gus, const int* __restrict__ rows,
    const float* __restrict__ rw, const int* __restrict__ te,
    u16* __restrict__ act) {
  const int tile = blockIdx.y;
  const int e = te[tile];
  if (e < 0) return;
  const int f0 = blockIdx.x * 64;

  __shared__ u16 sA[2][BM * LDK];
  __shared__ u16 sBg[2][64 * LDK];
  __shared__ u16 sBu[2][64 * LDK];
  __shared__ int rows_s[BM];
  __shared__ float rw_s[BM];

  const int tid = threadIdx.x;
  rows_s[tid] = rows[tile * BM + tid];
  rw_s[tid] = rw[tile * BM + tid];
  __syncthreads();

  int arow = rows_s[tid];
  arow = arow < 0 ? 0 : arow;
  const u16* aptr = xb + (size_t)arow * HD;
  const int lofsA = tid * LDK;

  const int bn = (tid & 127) >> 1;
  const int isUp = tid >> 7;
  const int o = isUp * 1024 + f0 + bn;
  const int skh = tid & 1;
  const int* bptr = gup32 + (size_t)(e * 2048 + o) * (HD / 2) + skh * 8;
  const uint32_t* sptr = gus + (size_t)(e * 2048 + o) * (HD / 32);
  const int lofsB = bn * LDK + skh * 16;

  const int lane = tid & 63;
  const int w = tid >> 6;
  const int q = lane >> 4, c = lane & 15;

  f32x4 Cg[4][4], Cu[4][4];
#pragma unroll
  for (int s = 0; s < 4; ++s)
#pragma unroll
    for (int t2 = 0; t2 < 4; ++t2) {
      Cg[s][t2] = f32x4{0.f, 0.f, 0.f, 0.f};
      Cu[s][t2] = f32x4{0.f, 0.f, 0.f, 0.f};
    }

  // prologue: stage K-step 0 into buffer 0
  {
    uint4 a0 = *(const uint4*)(aptr);
    uint4 a1 = *(const uint4*)(aptr + 8);
    uint4 a2 = *(const uint4*)(aptr + 16);
    uint4 a3 = *(const uint4*)(aptr + 24);
    int4 w0 = *(const int4*)(bptr);
    int4 w1 = *(const int4*)(bptr + 4);
    uint32_t sb = sptr[0];
    DqTab t = make_tab(sb);
    uint32_t d0[4], d1[4];
    dq8(pack4(w0), t, d0);
    dq8(pack4(w1), t, d1);
    u16* sAp = &sA[0][lofsA];
    *(uint4*)sAp = a0;
    *(uint4*)(sAp + 8) = a1;
    *(uint4*)(sAp + 16) = a2;
    *(uint4*)(sAp + 24) = a3;
    u16* sBp = (isUp ? sBu[0] : sBg[0]) + lofsB;
    *(uint4*)sBp = make_uint4(d0[0], d0[1], d0[2], d0[3]);
    *(uint4*)(sBp + 8) = make_uint4(d1[0], d1[1], d1[2], d1[3]);
  }

  for (int kk = 0; kk < HD / 32; ++kk) {
    const int p = kk & 1;
    __syncthreads();
    // prefetch K-step kk+1 into registers (overlaps with MFMA below)
    uint4 na0, na1, na2, na3;
    int4 nw0, nw1;
    uint32_t nsb;
    if (kk < HD / 32 - 1) {
      const int k2 = (kk + 1) * 32;
      na0 = *(const uint4*)(aptr + k2);
      na1 = *(const uint4*)(aptr + k2 + 8);
      na2 = *(const uint4*)(aptr + k2 + 16);
      na3 = *(const uint4*)(aptr + k2 + 24);
      nw0 = *(const int4*)(bptr + (k2 >> 1));
      nw1 = *(const int4*)(bptr + (k2 >> 1) + 4);
      nsb = sptr[k2 >> 5];
    }

    bf16x8 af[4], bg[4], bu[4];
#pragma unroll
    for (int s = 0; s < 4; ++s)
      af[s] = *(const bf16x8*)&sA[p][(w * 64 + s * 16 + c) * LDK + q * 8];
#pragma unroll
    for (int t2 = 0; t2 < 4; ++t2) {
      bg[t2] = *(const bf16x8*)&sBg[p][(t2 * 16 + c) * LDK + q * 8];
      bu[t2] = *(const bf16x8*)&sBu[p][(t2 * 16 + c) * LDK + q * 8];
    }
#pragma unroll
    for (int s = 0; s < 4; ++s)
#pragma unroll
      for (int t2 = 0; t2 < 4; ++t2) {
        Cg[s][t2] = __builtin_amdgcn_mfma_f32_16x16x32_bf16(af[s], bg[t2], Cg[s][t2], 0, 0, 0);
        Cu[s][t2] = __builtin_amdgcn_mfma_f32_16x16x32_bf16(af[s], bu[t2], Cu[s][t2], 0, 0, 0);
      }

    if (kk < HD / 32 - 1) {
      DqTab t = make_tab(nsb);
      uint32_t d0[4], d1[4];
      dq8(pack4(nw0), t, d0);
      dq8(pack4(nw1), t, d1);
      u16* sAp = &sA[p ^ 1][lofsA];
      *(uint4*)sAp = na0;
      *(uint4*)(sAp + 8) = na1;
      *(uint4*)(sAp + 16) = na2;
      *(uint4*)(sAp + 24) = na3;
      u16* sBp = (isUp ? sBu[p ^ 1] : sBg[p ^ 1]) + lofsB;
      *(uint4*)sBp = make_uint4(d0[0], d0[1], d0[2], d0[3]);
      *(uint4*)(sBp + 8) = make_uint4(d1[0], d1[1], d1[2], d1[3]);
    }
  }

#pragma unroll
  for (int s = 0; s < 4; ++s) {
    const int mlb = w * 64 + s * 16 + q * 4;
#pragma unroll
    for (int t2 = 0; t2 < 4; ++t2) {
      const int fg = f0 + t2 * 16 + c;
#pragma unroll
      for (int r = 0; r < 4; ++r) {
        const int ml = mlb + r;
        float g = Cg[s][t2][r];
        float u = Cu[s][t2][r];
        float aval = g / (1.f + __expf(-g)) * u * rw_s[ml];
        act[(size_t)(tile * BM + ml) * FD + fg] = f2bf(aval);
      }
    }
  }
}

// down GEMM, atomic accumulate into out. BM=256, BN=128, BK=32, double-buffered.
__global__ __launch_bounds__(256, 2) void gemm2_kernel(
    const u16* __restrict__ act, const int* __restrict__ dwn32,
    const uint32_t* __restrict__ dsc, const int* __restrict__ rows,
    const int* __restrict__ te, float* __restrict__ out) {
  const int tile = blockIdx.y;
  const int e = te[tile];
  if (e < 0) return;
  const int h0 = blockIdx.x * 128;

  __shared__ u16 sA[2][BM * LDK];
  __shared__ u16 sB[2][128 * LDK];
  __shared__ int rows_s[BM];

  const int tid = threadIdx.x;
  rows_s[tid] = rows[tile * BM + tid];
  __syncthreads();

  const u16* aptr = act + (size_t)(tile * BM + tid) * FD;
  const int lofsA = tid * LDK;

  const int bn = tid >> 1;
  const int skh = tid & 1;
  const int* bptr = dwn32 + (size_t)(e * 2048 + h0 + bn) * (FD / 2) + skh * 8;
  const uint32_t* sptr = dsc + (size_t)(e * 2048 + h0 + bn) * (FD / 32);
  const int lofsB = bn * LDK + skh * 16;

  const int lane = tid & 63;
  const int w = tid >> 6;
  const int q = lane >> 4, c = lane & 15;

  f32x4 Cd[4][8];
#pragma unroll
  for (int s = 0; s < 4; ++s)
#pragma unroll
    for (int t2 = 0; t2 < 8; ++t2) Cd[s][t2] = f32x4{0.f, 0.f, 0.f, 0.f};

  {
    uint4 a0 = *(const uint4*)(aptr);
    uint4 a1 = *(const uint4*)(aptr + 8);
    uint4 a2 = *(const uint4*)(aptr + 16);
    uint4 a3 = *(const uint4*)(aptr + 24);
    int4 w0 = *(const int4*)(bptr);
    int4 w1 = *(const int4*)(bptr + 4);
    uint32_t sb = sptr[0];
    DqTab t = make_tab(sb);
    uint32_t d0[4], d1[4];
    dq8(pack4(w0), t, d0);
    dq8(pack4(w1), t, d1);
    u16* sAp = &sA[0][lofsA];
    *(uint4*)sAp = a0;
    *(uint4*)(sAp + 8) = a1;
    *(uint4*)(sAp + 16) = a2;
    *(uint4*)(sAp + 24) = a3;
    u16* sBp = sB[0] + lofsB;
    *(uint4*)sBp = make_uint4(d0[0], d0[1], d0[2], d0[3]);
    *(uint4*)(sBp + 8) = make_uint4(d1[0], d1[1], d1[2], d1[3]);
  }

  for (int kk = 0; kk < FD / 32; ++kk) {
    const int p = kk & 1;
    __syncthreads();
    uint4 na0, na1, na2, na3;
    int4 nw0, nw1;
    uint32_t nsb;
    if (kk < FD / 32 - 1) {
      const int k2 = (kk + 1) * 32;
      na0 = *(const uint4*)(aptr + k2);
      na1 = *(const uint4*)(aptr + k2 + 8);
      na2 = *(const uint4*)(aptr + k2 + 16);
      na3 = *(const uint4*)(aptr + k2 + 24);
      nw0 = *(const int4*)(bptr + (k2 >> 1));
      nw1 = *(const int4*)(bptr + (k2 >> 1) + 4);
      nsb = sptr[k2 >> 5];
    }

    bf16x8 af[4], bf_[8];
#pragma unroll
    for (int s = 0; s < 4; ++s)
      af[s] = *(const bf16x8*)&sA[p][(w * 64 + s * 16 + c) * LDK + q * 8];
#pragma unroll
    for (int t2 = 0; t2 < 8; ++t2)
      bf_[t2] = *(const bf16x8*)&sB[p][(t2 * 16 + c) * LDK + q * 8];
#pragma unroll
    for (int s = 0; s < 4; ++s)
#pragma unroll
      for (int t2 = 0; t2 < 8; ++t2)
        Cd[s][t2] = __builtin_amdgcn_mfma_f32_16x16x32_bf16(af[s], bf_[t2], Cd[s][t2], 0, 0, 0);

    if (kk < FD / 32 - 1) {
      DqTab t = make_tab(nsb);
      uint32_t d0[4], d1[4];
      dq8(pack4(nw0), t, d0);
      dq8(pack4(nw1), t, d1);
      u16* sAp = &sA[p ^ 1][lofsA];
      *(uint4*)sAp = na0;
      *(uint4*)(sAp + 8) = na1;
      *(uint4*)(sAp + 16) = na2;
      *(uint4*)(sAp + 24) = na3;
      u16* sBp = sB[p ^ 1] + lofsB;
      *(uint4*)sBp = make_uint4(d0[0], d0[1], d0[2], d0[3]);
      *(uint4*)(sBp + 8) = make_uint4(d1[0], d1[1], d1[2], d1[3]);
    }
  }

#pragma unroll
  for (int s = 0; s < 4; ++s) {
    const int mlb = w * 64 + s * 16 + q * 4;
#pragma unroll
    for (int t2 = 0; t2 < 8; ++t2) {
      const int hg = h0 + t2 * 16 + c;
#pragma unroll
      for (int r = 0; r < 4; ++r) {
        int token = rows_s[mlb + r];
        if (token >= 0) atomicAdd(&out[(size_t)token * HD + hg], Cd[s][t2][r]);
      }
    }
  }
}

extern "C" void kernel_launch(void* const* d_in, const int* in_sizes, int n_in,
                              void* d_out, int out_size, void* d_ws, size_t ws_size,
                              hipStream_t stream) {
  const float* hidden = (const float*)d_in[0];
  const float* tw = (const float*)d_in[1];
  const int* ids = (const int*)d_in[2];
  const int* gup32 = (const int*)d_in[3];        // uint8 packed bytes, uploaded as int32
  const uint32_t* gus = (const uint32_t*)d_in[4];
  const int* dwn32 = (const int*)d_in[5];
  const uint32_t* dsc = (const uint32_t*)d_in[6];
  float* out = (float*)d_out;

  char* ws = (char*)d_ws;
  int* rows = (int*)(ws);                    // 48 KB
  float* rw = (float*)(ws + 49152);          // 48 KB
  int* te = (int*)(ws + 98304);              // 192 B
  u16* xb = (u16*)(ws + 131072);             // 8 MB
  u16* act = (u16*)(ws + 8519680);           // ~20 MB actually written; < 29.5 MB known-safe

  cast_kernel<<<dim3(4096), dim3(256), 0, stream>>>(hidden, xb);
  zero_kernel<<<dim3(4096), dim3(256), 0, stream>>>((float4*)out);
  route_kernel<<<dim3(1), dim3(256), 0, stream>>>(ids, tw, rows, rw, te);
  gemm1_kernel<<<dim3(16, MAXT), dim3(256), 0, stream>>>(xb, gup32, gus, rows, rw, te, act);
  gemm2_kernel<<<dim3(16, MAXT), dim3(256), 0, stream>>>(act, dwn32, dsc, rows, te, out);
}